// Round 14
// baseline (12850.981 us; speedup 1.0000x reference)
//
#include <hip/hip_runtime.h>
#include <stdint.h>

// GRU scan, persistent cooperative kernel, round 14.
// = round 13 (TLP: NB=512, 2 blocks/CU, 64 clusters x 16 batch rows x 8
// blocks, single-phase step, 1 barrier/step, round 8's schedule) with ONE
// change: the cluster mapping keeps each cluster's 8 blocks on ONE XCD.
//   Round 13's regression diagnosis: c=bid>>3 scattered clusters across XCDs
//   -> FETCH 1.1->8.9 GB (staging reads went remote). Rounds 7/8's c=bid&N
//   accidentally made clusters XCD-local (all blocks = c mod 8 -> same XCD
//   under round-robin dispatch) -> exchange lived in the shared local L2.
//   New mapping: c = (bid&7)*8 + (bid>>6), g = (bid>>3)&7:
//     cluster blocks = {(bid&7) + 64*(bid>>6) + 8j, j=0..7} -> same XCD;
//     co-resident pairs (b, b+256) -> different clusters -> TLP interleaves.
// Coherence (proven r5-r13): write-through h stores (RELAXED/AGENT), aux=17
// read-through staging, relaxed per-wave flags, no fences. Anti-race: each
// wave posts only after vmcnt(0) drains its stores (logits store data-depends
// on its last LDS reads); staging gated on all 32 cluster flags.

#define NB 512
#define NT 256
#define TB 1024
#define TT 2048
#define II 12
#define HH 512
#define NCL 64
#define GBLK 8
#define ROWS 16

#define HTILE_B (ROWS * HH * 2)               // 16 KiB per cluster per buffer
#define HBUF_B  ((size_t)NCL * HTILE_B)       // 1 MiB per buffer
#define BAR_OFF ((size_t)2 * HBUF_B)
#define WS_USED (BAR_OFF + (size_t)NCL * 128) // 32 flag words per cluster

#define LDSB (ROWS * 1024)                    // 16 KiB A-tile

#define GAS __attribute__((address_space(1)))
#define LAS __attribute__((address_space(3)))

typedef _Float16 half8 __attribute__((ext_vector_type(8)));
typedef float    f32x4 __attribute__((ext_vector_type(4)));

static __device__ __forceinline__ float fast_sigmoid(float x) {
  float e = exp2f(-1.44269504f * x);
  return __builtin_amdgcn_rcpf(1.0f + e);
}
static __device__ __forceinline__ float fast_tanh(float x) {
  float e = exp2f(2.88539008f * x);           // exp(2x)
  return 1.0f - 2.0f * __builtin_amdgcn_rcpf(1.0f + e);
}

// Blocking poll of 32 per-wave flag words, lane-parallel, relaxed agent.
static __device__ __forceinline__ void wait_flags32(unsigned* f, unsigned tgt,
                                                    int* dead) {
  const int l = threadIdx.x & 63;
  long spin = 0;
  for (;;) {
    unsigned v = __hip_atomic_load(f + (l & 31), __ATOMIC_RELAXED,
                                   __HIP_MEMORY_SCOPE_AGENT);
    if (__all(v >= tgt)) break;
    if (++spin > (1L << 24)) { *dead = 1; break; }
  }
}

__global__ void __launch_bounds__(NT, 1)
gru_persistent(const float* __restrict__ hist,
               const float* __restrict__ w_ih,
               const float* __restrict__ w_hh,
               const float* __restrict__ w_out,
               const float* __restrict__ b_out,
               float* __restrict__ out,
               uint8_t* __restrict__ ws)
{
  extern __shared__ char smem[];
  char* ldsA = smem;
  const int bid = blockIdx.x;
  // XCD-local clustering: all 8 blocks of a cluster share bid&7 (same XCD
  // under round-robin dispatch); co-resident (b, b+256) -> different clusters.
  const int c   = (bid & 7) * 8 + (bid >> 6);   // cluster (64)
  const int g   = (bid >> 3) & 7;               // block within cluster (8)
  const int tid = threadIdx.x;
  const int w   = tid >> 6;          // wave 0..3 -> col-tile
  const int l   = tid & 63;
  const int l15 = l & 15;
  const int l4  = l >> 4;
  const int crb = c * ROWS;
  unsigned* F = (unsigned*)(ws + BAR_OFF) + (size_t)c * 32;   // 32 words
  const int myflag = g * 4 + w;

  const int col0 = g * 64 + w * 16;  // wave's 16 output cols
  const int pcol = col0 + l15;

  // ---- W_hh register B-fragments for r,z,n (16 K-slices each, static idx)
  half8 wr[16], wz[16], wn[16];
#pragma unroll
  for (int ks = 0; ks < 16; ++ks) {
    const size_t Rr = (size_t)(0 * HH + col0 + l15) * HH + ks * 32 + l4 * 8;
    const size_t Rz = (size_t)(1 * HH + col0 + l15) * HH + ks * 32 + l4 * 8;
    const size_t Rn = (size_t)(2 * HH + col0 + l15) * HH + ks * 32 + l4 * 8;
#pragma unroll
    for (int i = 0; i < 8; ++i) {
      wr[ks][i] = (_Float16)w_hh[Rr + i];
      wz[ks][i] = (_Float16)w_hh[Rz + i];
      wn[ks][i] = (_Float16)w_hh[Rn + i];
    }
  }

  // ---- w_ih register B-fragments (K window = x cols 0..31)
  half8 wih[3];
#pragma unroll
  for (int gt = 0; gt < 3; ++gt) {
    const int R = gt * HH + col0 + l15;
#pragma unroll
    for (int i = 0; i < 8; ++i) {
      const int k = l4 * 8 + i;
      wih[gt][i] = (_Float16)((k < II) ? w_ih[R * II + k] : 0.0f);
    }
  }

  // ---- logits: wave myflag -> row erow, output jj; lane l holds
  //      w_out[jj][l*8 .. l*8+7]; full 64-lane reduce. 32 slots = 16 rows x 2.
  const int jj   = myflag & 1;
  const int erow = myflag >> 1;
  float wor8[8];
#pragma unroll
  for (int i = 0; i < 8; ++i) wor8[i] = w_out[jj * HH + l * 8 + i];
  const float bo = b_out[jj];

  float hprev[4];
#pragma unroll
  for (int q = 0; q < 4; ++q) hprev[q] = 0.0f;

  int deadlock = 0;

  // ---- prologue: issue x(0) prefetch (retires by first use at C)
  f32x4 xn0 = (f32x4){0.f, 0.f, 0.f, 0.f};
  f32x4 xn1 = (f32x4){0.f, 0.f, 0.f, 0.f};
  {
    const float* xp = hist + (size_t)(crb + l15) * (TT * II);
    if (l4 == 0)      { xn0 = *(const f32x4*)xp; xn1 = *(const f32x4*)(xp + 4); }
    else if (l4 == 1) { xn0 = *(const f32x4*)(xp + 8); }
  }

  for (int t = 0; t < TT; ++t) {
    const uint8_t* hsrc = ws + ((t & 1) ? HBUF_B : 0) + (size_t)c * HTILE_B;
    uint8_t*       hdst = ws + ((t & 1) ? 0 : HBUF_B) + (size_t)c * HTILE_B;

    // A: wait cluster flags(t) — all 32 waves posted h(t)
    if (t > 0) wait_flags32(F, (unsigned)t, &deadlock);
    __builtin_amdgcn_sched_barrier(0);

    // B: issue stage of full 16-row tile (4 insts)     [out: x3 + s4]
#pragma unroll
    for (int it = 0; it < 4; ++it)
      __builtin_amdgcn_global_load_lds(
          (const GAS uint32_t*)(hsrc + it * 4096 + tid * 16),
          (LAS uint32_t*)(ldsA + it * 4096 + tid * 16), 16, 0, 17);
    __builtin_amdgcn_sched_barrier(0);

    // C: build ax(t) from prefetch (compiler waits x3 only); issue x(t+1)
    half8 ax;
#pragma unroll
    for (int i = 0; i < 4; ++i) {
      ax[i]     = (_Float16)xn0[i];
      ax[4 + i] = (_Float16)xn1[i];
    }
    {
      const int tx = (t + 1 < TT) ? (t + 1) : 0;
      const float* xp = hist + (size_t)(crb + l15) * (TT * II) + (size_t)tx * II;
      if (l4 == 0)      { xn0 = *(const f32x4*)xp; xn1 = *(const f32x4*)(xp + 4); }
      else if (l4 == 1) { xn0 = *(const f32x4*)(xp + 8); }
    }
    __builtin_amdgcn_sched_barrier(0);

    // D: vmcnt(3) -> stage retired (x(t+1) outstanding) -> barrier
    asm volatile("s_waitcnt vmcnt(3)" ::: "memory");
    __builtin_amdgcn_s_barrier();
    __builtin_amdgcn_sched_barrier(0);

    // E: MFMAs — x contribution + 16 K-slices x 3 gates
    f32x4 acc0 = (f32x4){0.f, 0.f, 0.f, 0.f};
    f32x4 acc1 = acc0, acc2 = acc0;
    f32x4 accin = __builtin_amdgcn_mfma_f32_16x16x32_f16(ax, wih[2],
                    (f32x4){0.f, 0.f, 0.f, 0.f}, 0, 0, 0);
    acc0 = __builtin_amdgcn_mfma_f32_16x16x32_f16(ax, wih[0], acc0, 0, 0, 0);
    acc1 = __builtin_amdgcn_mfma_f32_16x16x32_f16(ax, wih[1], acc1, 0, 0, 0);
#pragma unroll
    for (int ks = 0; ks < 16; ++ks) {
      const int ko = (ks * 64 + l4 * 16) ^ ((l15 & 7) << 4);
      half8 a = *(const half8*)(ldsA + l15 * 1024 + ko);
      acc0 = __builtin_amdgcn_mfma_f32_16x16x32_f16(a, wr[ks], acc0, 0, 0, 0);
      acc1 = __builtin_amdgcn_mfma_f32_16x16x32_f16(a, wz[ks], acc1, 0, 0, 0);
      acc2 = __builtin_amdgcn_mfma_f32_16x16x32_f16(a, wn[ks], acc2, 0, 0, 0);
    }

    // F: gates + h stores rows 0-15 (write-through, pre-swizzled)
#pragma unroll
    for (int q = 0; q < 4; ++q) {
      const int m = l4 * 4 + q;
      const float r  = fast_sigmoid(acc0[q]);
      const float z  = fast_sigmoid(acc1[q]);
      const float n  = fast_tanh(accin[q] + r * acc2[q]);
      const float hn = (1.0f - z) * n + z * hprev[q];
      hprev[q] = hn;
      __hip_atomic_store(
          (unsigned short*)(hdst + m * 1024 + ((pcol * 2) ^ ((m & 7) << 4))),
          __builtin_bit_cast(unsigned short, (_Float16)hn),
          __ATOMIC_RELAXED, __HIP_MEMORY_SCOPE_AGENT);
    }

    // G: logits(t-1) from h(t) in LDS — one dot per wave (row erow, out jj)
    if (t > 0) {
      float s = 0.0f;
      half8 hv = *(const half8*)(ldsA + erow * 1024 + ((l * 16) ^ ((erow & 7) << 4)));
#pragma unroll
      for (int i = 0; i < 8; ++i) s += (float)hv[i] * wor8[i];
#pragma unroll
      for (int off = 1; off < 64; off <<= 1) s += __shfl_xor(s, off);
      if (l == 0) out[((size_t)(crb + erow) * TT + (t - 1)) * 2 + jj] = s + bo;
    }
    __builtin_amdgcn_sched_barrier(0);

    // H: drain (h stores + logits store; x long retired) -> post flag
    asm volatile("s_waitcnt vmcnt(0)" ::: "memory");
    __builtin_amdgcn_sched_barrier(0);
    if (l == 0)
      __hip_atomic_store(F + myflag, (unsigned)(t + 1), __ATOMIC_RELAXED,
                         __HIP_MEMORY_SCOPE_AGENT);
  }

  // ================= epilogue: h(TT) logits + h_final ======================
  wait_flags32(F, (unsigned)TT, &deadlock);
  {
    const uint8_t* hsrc = ws + ((TT & 1) ? HBUF_B : 0) + (size_t)c * HTILE_B;
#pragma unroll
    for (int it = 0; it < 4; ++it)
      __builtin_amdgcn_global_load_lds(
          (const GAS uint32_t*)(hsrc + it * 4096 + tid * 16),
          (LAS uint32_t*)(ldsA + it * 4096 + tid * 16), 16, 0, 17);
    asm volatile("s_waitcnt vmcnt(0)" ::: "memory");
    __builtin_amdgcn_s_barrier();

    float s = 0.0f;
    half8 hv = *(const half8*)(ldsA + erow * 1024 + ((l * 16) ^ ((erow & 7) << 4)));
#pragma unroll
    for (int i = 0; i < 8; ++i) s += (float)hv[i] * wor8[i];
#pragma unroll
    for (int off = 1; off < 64; off <<= 1) s += __shfl_xor(s, off);
    if (l == 0) out[((size_t)(crb + erow) * TT + (TT - 1)) * 2 + jj] = s + bo;
  }

  // ---- h_final from fp32 carried state
#pragma unroll
  for (int q = 0; q < 4; ++q) {
    const int m = l4 * 4 + q;
    out[(size_t)TB * TT * 2 + (size_t)(crb + m) * HH + pcol] = hprev[q];
  }
}

extern "C" void kernel_launch(void* const* d_in, const int* in_sizes, int n_in,
                              void* d_out, int out_size, void* d_ws, size_t ws_size,
                              hipStream_t stream) {
  (void)in_sizes; (void)n_in; (void)out_size;
  if (ws_size < WS_USED) return;

  const float* hist  = (const float*)d_in[0];
  const float* w_ih  = (const float*)d_in[1];
  const float* w_hh  = (const float*)d_in[2];
  const float* w_out = (const float*)d_in[3];
  const float* b_out = (const float*)d_in[4];
  float* out = (float*)d_out;
  uint8_t* ws = (uint8_t*)d_ws;

  hipMemsetAsync(d_ws, 0, WS_USED, stream);   // h0 = 0, flag words

  void* args[] = {(void*)&hist, (void*)&w_ih, (void*)&w_hh, (void*)&w_out,
                  (void*)&b_out, (void*)&out, (void*)&ws};
  hipError_t e = hipLaunchCooperativeKernel((const void*)gru_persistent,
                                            dim3(NB), dim3(NT), args,
                                            (unsigned)LDSB, stream);
  if (e != hipSuccess) {
    // Fallback: plain launch. 512 blocks at 2/CU co-reside (16KB LDS, ~230
    // VGPR); every spin loop has a deadlock bail-out so this cannot hang.
    gru_persistent<<<dim3(NB), dim3(NT), LDSB, stream>>>(
        hist, w_ih, w_hh, w_out, b_out, out, ws);
  }
}

// Round 15
// 8872.499 us; speedup vs baseline: 1.4484x; 1.4484x over previous
//
#include <hip/hip_runtime.h>
#include <stdint.h>

// GRU scan, persistent cooperative kernel, round 15.
// = round 8 EXACTLY (NB=256, 1 block/CU, 32 clusters x 32 rows x 8 blocks,
// c=bid&31 -> XCD-local clusters, 2-phase, fresh poll, x at top, single end
// drain) — proven best macro-structure (r9-r14 refuted skew/ledger/TLP/XCD
// alternatives) — plus three serial-chain shavings:
//  1) 4-bit LDS swizzle (row&15)<<4 (was (row&7)<<4): kills the ~4-way
//     ds_read_b128 conflicts (3.7e8 conflict cycles ~ 0.2us/step).
//  2) logits moved inside the MFMA phase regions (early rows 0-15 / late
//     rows 16-31) — VALU overlaps MFMA issue, off the step-end chain.
//  3) per-wave flags (32/cluster), posted right after each wave's vmcnt(0);
//     3rd barrier removed. Anti-race: staging gated on all 32 flags; each
//     wave's flag follows its last LDS read of the step.
// Coherence (proven r5-r14): write-through h stores (RELAXED/AGENT), aux=17
// read-through staging, relaxed flags, no fences.

#define NB 256
#define NT 256
#define TB 1024
#define TT 2048
#define II 12
#define HH 512
#define NCL 32
#define GBLK 8
#define ROWS 32

#define HTILE_B (ROWS * HH * 2)               // 32 KiB per cluster per buffer
#define HBUF_B  ((size_t)NCL * HTILE_B)       // 1 MiB per buffer
#define BAR_OFF ((size_t)2 * HBUF_B)
#define WS_USED (BAR_OFF + (size_t)NCL * 128) // 32 flag words per cluster

#define LDSB (ROWS * 1024)                    // 32 KiB A-tile

#define GAS __attribute__((address_space(1)))
#define LAS __attribute__((address_space(3)))

typedef _Float16 half8 __attribute__((ext_vector_type(8)));
typedef float    f32x4 __attribute__((ext_vector_type(4)));

static __device__ __forceinline__ float fast_sigmoid(float x) {
  float e = exp2f(-1.44269504f * x);
  return __builtin_amdgcn_rcpf(1.0f + e);
}
static __device__ __forceinline__ float fast_tanh(float x) {
  float e = exp2f(2.88539008f * x);           // exp(2x)
  return 1.0f - 2.0f * __builtin_amdgcn_rcpf(1.0f + e);
}

// Blocking poll of 32 per-wave flag words, lane-parallel, relaxed agent.
static __device__ __forceinline__ void wait_flags32(unsigned* f, unsigned tgt,
                                                    int* dead) {
  const int l = threadIdx.x & 63;
  long spin = 0;
  for (;;) {
    unsigned v = __hip_atomic_load(f + (l & 31), __ATOMIC_RELAXED,
                                   __HIP_MEMORY_SCOPE_AGENT);
    if (__all(v >= tgt)) break;
    if (++spin > (1L << 24)) { *dead = 1; break; }
  }
}

__global__ void __launch_bounds__(NT, 1)
gru_persistent(const float* __restrict__ hist,
               const float* __restrict__ w_ih,
               const float* __restrict__ w_hh,
               const float* __restrict__ w_out,
               const float* __restrict__ b_out,
               float* __restrict__ out,
               uint8_t* __restrict__ ws)
{
  extern __shared__ char smem[];
  char* ldsA = smem;
  const int bid = blockIdx.x;
  const int c   = bid & 31;          // cluster (32) — XCD-local (all = c mod 8)
  const int g   = bid >> 5;          // block within cluster (8)
  const int tid = threadIdx.x;
  const int w   = tid >> 6;          // wave 0..3 -> col-tile
  const int l   = tid & 63;
  const int l15 = l & 15;
  const int l4  = l >> 4;
  const int crb = c * ROWS;
  unsigned* F = (unsigned*)(ws + BAR_OFF) + (size_t)c * 32;   // 32 words
  const int myflag = g * 4 + w;

  const int col0 = g * 64 + w * 16;  // wave's 16 output cols
  const int pcol = col0 + l15;

  // ---- W_hh register B-fragments for r,z,n (16 K-slices each, static idx)
  half8 wr[16], wz[16], wn[16];
#pragma unroll
  for (int ks = 0; ks < 16; ++ks) {
    const size_t Rr = (size_t)(0 * HH + col0 + l15) * HH + ks * 32 + l4 * 8;
    const size_t Rz = (size_t)(1 * HH + col0 + l15) * HH + ks * 32 + l4 * 8;
    const size_t Rn = (size_t)(2 * HH + col0 + l15) * HH + ks * 32 + l4 * 8;
#pragma unroll
    for (int i = 0; i < 8; ++i) {
      wr[ks][i] = (_Float16)w_hh[Rr + i];
      wz[ks][i] = (_Float16)w_hh[Rz + i];
      wn[ks][i] = (_Float16)w_hh[Rn + i];
    }
  }

  // ---- w_ih register B-fragments (K window = x cols 0..31)
  half8 wih[3];
#pragma unroll
  for (int gt = 0; gt < 3; ++gt) {
    const int R = gt * HH + col0 + l15;
#pragma unroll
    for (int i = 0; i < 8; ++i) {
      const int k = l4 * 8 + i;
      wih[gt][i] = (_Float16)((k < II) ? w_ih[R * II + k] : 0.0f);
    }
  }

  // ---- logits: wave handles row lr = g*4+w; lanes split jj=(l>>4)&1;
  //      lane group l15 covers h cols [l15*32, l15*32+32)
  const int lr = g * 4 + w;          // 0..31
  const int jj = (l >> 4) & 1;
  float wor[32];
#pragma unroll
  for (int i = 0; i < 32; ++i) wor[i] = w_out[jj * HH + l15 * 32 + i];
  const float bo = b_out[jj];

  float hprev[2][4];
#pragma unroll
  for (int mt = 0; mt < 2; ++mt)
#pragma unroll
    for (int q = 0; q < 4; ++q) hprev[mt][q] = 0.0f;

  int deadlock = 0;

  // ---- prologue: issue x(0) prefetch
  f32x4 xn0[2], xn1[2];
#pragma unroll
  for (int mt = 0; mt < 2; ++mt) {
    xn0[mt] = (f32x4){0.f, 0.f, 0.f, 0.f};
    xn1[mt] = (f32x4){0.f, 0.f, 0.f, 0.f};
    const float* xp = hist + (size_t)(crb + mt * 16 + l15) * (TT * II);
    if (l4 == 0)      { xn0[mt] = *(const f32x4*)xp; xn1[mt] = *(const f32x4*)(xp + 4); }
    else if (l4 == 1) { xn0[mt] = *(const f32x4*)(xp + 8); }
  }

  for (int t = 0; t < TT; ++t) {
    const uint8_t* hsrc = ws + ((t & 1) ? HBUF_B : 0) + (size_t)c * HTILE_B;
    uint8_t*       hdst = ws + ((t & 1) ? 0 : HBUF_B) + (size_t)c * HTILE_B;

    // A: wait all 32 cluster flags (fresh poll — proven fastest form)
    if (t > 0) wait_flags32(F, (unsigned)t, &deadlock);
    __builtin_amdgcn_sched_barrier(0);

    // B: issue stage rows 0-31 (8 insts; lo = first 4)
#pragma unroll
    for (int it = 0; it < 8; ++it)
      __builtin_amdgcn_global_load_lds(
          (const GAS uint32_t*)(hsrc + it * 4096 + tid * 16),
          (LAS uint32_t*)(ldsA + it * 4096 + tid * 16), 16, 0, 17);
    __builtin_amdgcn_sched_barrier(0);

    // C: build ax(t) from prefetch; issue x(t+1)
    half8 ax[2];
#pragma unroll
    for (int mt = 0; mt < 2; ++mt)
#pragma unroll
      for (int i = 0; i < 4; ++i) {
        ax[mt][i]     = (_Float16)xn0[mt][i];
        ax[mt][4 + i] = (_Float16)xn1[mt][i];
      }
    {
      const int tx = (t + 1 < TT) ? (t + 1) : 0;
#pragma unroll
      for (int mt = 0; mt < 2; ++mt) {
        const float* xp = hist + (size_t)(crb + mt * 16 + l15) * (TT * II) + (size_t)tx * II;
        if (l4 == 0)      { xn0[mt] = *(const f32x4*)xp; xn1[mt] = *(const f32x4*)(xp + 4); }
        else if (l4 == 1) { xn0[mt] = *(const f32x4*)(xp + 8); }
      }
    }
    __builtin_amdgcn_sched_barrier(0);

    // D: vmcnt(10) -> lo staged (hi4 + x6 outstanding) -> barrier
    asm volatile("s_waitcnt vmcnt(10)" ::: "memory");
    __builtin_amdgcn_s_barrier();
    __builtin_amdgcn_sched_barrier(0);

    // ======== phase 1: rows 0-15 (mt=0) ========
    f32x4 acc0 = (f32x4){0.f, 0.f, 0.f, 0.f};
    f32x4 acc1 = acc0, acc2 = acc0;
    f32x4 accin = __builtin_amdgcn_mfma_f32_16x16x32_f16(ax[0], wih[2],
                    (f32x4){0.f, 0.f, 0.f, 0.f}, 0, 0, 0);
    acc0 = __builtin_amdgcn_mfma_f32_16x16x32_f16(ax[0], wih[0], acc0, 0, 0, 0);
    acc1 = __builtin_amdgcn_mfma_f32_16x16x32_f16(ax[0], wih[1], acc1, 0, 0, 0);
#pragma unroll
    for (int ks = 0; ks < 16; ++ks) {
      const int ko = (ks * 64 + l4 * 16) ^ (l15 << 4);   // 4-bit swizzle
      half8 a = *(const half8*)(ldsA + l15 * 1024 + ko);
      acc0 = __builtin_amdgcn_mfma_f32_16x16x32_f16(a, wr[ks], acc0, 0, 0, 0);
      acc1 = __builtin_amdgcn_mfma_f32_16x16x32_f16(a, wz[ks], acc1, 0, 0, 0);
      acc2 = __builtin_amdgcn_mfma_f32_16x16x32_f16(a, wn[ks], acc2, 0, 0, 0);
    }

    // EARLY logits (t-1), rows 0-15 (blocks g<4) — overlaps phase-1 MFMA
    if (t > 0 && lr < 16) {
      float s = 0.0f;
#pragma unroll
      for (int c8 = 0; c8 < 4; ++c8) {
        half8 hv = *(const half8*)(ldsA + lr * 1024 +
                                   ((l15 * 64 + c8 * 16) ^ ((lr & 15) << 4)));
#pragma unroll
        for (int i = 0; i < 8; ++i) s += (float)hv[i] * wor[c8 * 8 + i];
      }
#pragma unroll
      for (int off = 1; off < 16; off <<= 1) s += __shfl_xor(s, off);
      if (l15 == 0 && l < 32) out[((size_t)(crb + lr) * TT + (t - 1)) * 2 + jj] = s + bo;
    }

    // gates + stores rows 0-15 (write-through, 4-bit pre-swizzle)
#pragma unroll
    for (int q = 0; q < 4; ++q) {
      const int m = l4 * 4 + q;
      const float r  = fast_sigmoid(acc0[q]);
      const float z  = fast_sigmoid(acc1[q]);
      const float n  = fast_tanh(accin[q] + r * acc2[q]);
      const float hn = (1.0f - z) * n + z * hprev[0][q];
      hprev[0][q] = hn;
      __hip_atomic_store(
          (unsigned short*)(hdst + m * 1024 + ((pcol * 2) ^ ((m & 15) << 4))),
          __builtin_bit_cast(unsigned short, (_Float16)hn),
          __ATOMIC_RELAXED, __HIP_MEMORY_SCOPE_AGENT);
    }
    __builtin_amdgcn_sched_barrier(0);

    // mid: vmcnt(10) -> hi staged -> barrier
    asm volatile("s_waitcnt vmcnt(10)" ::: "memory");
    __builtin_amdgcn_s_barrier();
    __builtin_amdgcn_sched_barrier(0);

    // ======== phase 2: rows 16-31 (mt=1) ========
    acc0 = (f32x4){0.f, 0.f, 0.f, 0.f};
    acc1 = acc0; acc2 = acc0;
    accin = __builtin_amdgcn_mfma_f32_16x16x32_f16(ax[1], wih[2],
              (f32x4){0.f, 0.f, 0.f, 0.f}, 0, 0, 0);
    acc0 = __builtin_amdgcn_mfma_f32_16x16x32_f16(ax[1], wih[0], acc0, 0, 0, 0);
    acc1 = __builtin_amdgcn_mfma_f32_16x16x32_f16(ax[1], wih[1], acc1, 0, 0, 0);
#pragma unroll
    for (int ks = 0; ks < 16; ++ks) {
      const int ko = (ks * 64 + l4 * 16) ^ (l15 << 4);   // (row&15)=l15 here too
      half8 a = *(const half8*)(ldsA + (16 + l15) * 1024 + ko);
      acc0 = __builtin_amdgcn_mfma_f32_16x16x32_f16(a, wr[ks], acc0, 0, 0, 0);
      acc1 = __builtin_amdgcn_mfma_f32_16x16x32_f16(a, wz[ks], acc1, 0, 0, 0);
      acc2 = __builtin_amdgcn_mfma_f32_16x16x32_f16(a, wn[ks], acc2, 0, 0, 0);
    }

    // LATE logits (t-1), rows 16-31 (blocks g>=4) — overlaps phase-2 MFMA
    if (t > 0 && lr >= 16) {
      float s = 0.0f;
#pragma unroll
      for (int c8 = 0; c8 < 4; ++c8) {
        half8 hv = *(const half8*)(ldsA + lr * 1024 +
                                   ((l15 * 64 + c8 * 16) ^ ((lr & 15) << 4)));
#pragma unroll
        for (int i = 0; i < 8; ++i) s += (float)hv[i] * wor[c8 * 8 + i];
      }
#pragma unroll
      for (int off = 1; off < 16; off <<= 1) s += __shfl_xor(s, off);
      if (l15 == 0 && l < 32) out[((size_t)(crb + lr) * TT + (t - 1)) * 2 + jj] = s + bo;
    }

    // gates + stores rows 16-31
#pragma unroll
    for (int q = 0; q < 4; ++q) {
      const int m = 16 + l4 * 4 + q;
      const float r  = fast_sigmoid(acc0[q]);
      const float z  = fast_sigmoid(acc1[q]);
      const float n  = fast_tanh(accin[q] + r * acc2[q]);
      const float hn = (1.0f - z) * n + z * hprev[1][q];
      hprev[1][q] = hn;
      __hip_atomic_store(
          (unsigned short*)(hdst + m * 1024 + ((pcol * 2) ^ ((m & 15) << 4))),
          __builtin_bit_cast(unsigned short, (_Float16)hn),
          __ATOMIC_RELAXED, __HIP_MEMORY_SCOPE_AGENT);
    }
    __builtin_amdgcn_sched_barrier(0);

    // end: drain all (stores + x) -> per-wave flag post (no 3rd barrier;
    // anti-race: this wave's last LDS reads precede this post, and next-step
    // staging waits on ALL 32 flags incl. same-block waves)
    asm volatile("s_waitcnt vmcnt(0)" ::: "memory");
    __builtin_amdgcn_sched_barrier(0);
    if (l == 0)
      __hip_atomic_store(F + myflag, (unsigned)(t + 1), __ATOMIC_RELAXED,
                         __HIP_MEMORY_SCOPE_AGENT);
  }

  // ================= epilogue: h(TT) logits + h_final ======================
  wait_flags32(F, (unsigned)TT, &deadlock);
  {
    const uint8_t* hsrc = ws + ((TT & 1) ? HBUF_B : 0) + (size_t)c * HTILE_B;
#pragma unroll
    for (int it = 0; it < 8; ++it)
      __builtin_amdgcn_global_load_lds(
          (const GAS uint32_t*)(hsrc + it * 4096 + tid * 16),
          (LAS uint32_t*)(ldsA + it * 4096 + tid * 16), 16, 0, 17);
    asm volatile("s_waitcnt vmcnt(0)" ::: "memory");
    __builtin_amdgcn_s_barrier();

    float s = 0.0f;
#pragma unroll
    for (int c8 = 0; c8 < 4; ++c8) {
      half8 hv = *(const half8*)(ldsA + lr * 1024 +
                                 ((l15 * 64 + c8 * 16) ^ ((lr & 15) << 4)));
#pragma unroll
      for (int i = 0; i < 8; ++i) s += (float)hv[i] * wor[c8 * 8 + i];
    }
#pragma unroll
    for (int off = 1; off < 16; off <<= 1) s += __shfl_xor(s, off);
    if (l15 == 0 && l < 32) out[((size_t)(crb + lr) * TT + (TT - 1)) * 2 + jj] = s + bo;
  }

  // ---- h_final from fp32 carried state
#pragma unroll
  for (int mt = 0; mt < 2; ++mt)
#pragma unroll
    for (int q = 0; q < 4; ++q) {
      const int m = mt * 16 + l4 * 4 + q;
      out[(size_t)TB * TT * 2 + (size_t)(crb + m) * HH + pcol] = hprev[mt][q];
    }
}

extern "C" void kernel_launch(void* const* d_in, const int* in_sizes, int n_in,
                              void* d_out, int out_size, void* d_ws, size_t ws_size,
                              hipStream_t stream) {
  (void)in_sizes; (void)n_in; (void)out_size;
  if (ws_size < WS_USED) return;

  const float* hist  = (const float*)d_in[0];
  const float* w_ih  = (const float*)d_in[1];
  const float* w_hh  = (const float*)d_in[2];
  const float* w_out = (const float*)d_in[3];
  const float* b_out = (const float*)d_in[4];
  float* out = (float*)d_out;
  uint8_t* ws = (uint8_t*)d_ws;

  hipMemsetAsync(d_ws, 0, WS_USED, stream);   // h0 = 0, flag words

  void* args[] = {(void*)&hist, (void*)&w_ih, (void*)&w_hh, (void*)&w_out,
                  (void*)&b_out, (void*)&out, (void*)&ws};
  hipError_t e = hipLaunchCooperativeKernel((const void*)gru_persistent,
                                            dim3(NB), dim3(NT), args,
                                            (unsigned)LDSB, stream);
  if (e != hipSuccess) {
    // Fallback: plain launch. 256 blocks at 1/CU co-reside; every spin loop
    // has a deadlock bail-out so this cannot hang.
    gru_persistent<<<dim3(NB), dim3(NT), LDSB, stream>>>(
        hist, w_ih, w_hh, w_out, b_out, out, ws);
  }
}

// Round 16
// 7938.789 us; speedup vs baseline: 1.6188x; 1.1176x over previous
//
#include <hip/hip_runtime.h>
#include <stdint.h>

// GRU scan, persistent cooperative kernel, round 16.
// = round 8 VERBATIM (best measured: 8.35ms profiled; NB=256, 1 block/CU,
// 32 clusters x 32 rows x 8 blocks, c=bid&31 -> XCD-local, 2-phase, fresh
// 8-word poll, per-block flags posted by tid0 after end barrier, logits at
// step end) + exactly two evidenced changes:
//  1) 4-bit LDS swizzle (r15 counter signature: conflicts 3.7e8 -> 1.0e8).
//  2) gates-lo moved into the phase-2 region with SEPARATE phase-2 acc regs:
//     its transcendental VALU interleaves with phase-2 MFMA issue (separate
//     pipes, m114). Mid wait becomes counted vmcnt(6). Logits in the same
//     overlap region (round 8 position relative to stores kept).
// r15's regressions NOT carried: per-wave flags / no-end-barrier / divergent
// early-late logits split.
// Coherence (proven r5-r15): write-through h stores (RELAXED/AGENT), aux=17
// read-through staging, relaxed flags, no fences.

#define NB 256
#define NT 256
#define TB 1024
#define TT 2048
#define II 12
#define HH 512
#define NCL 32
#define GBLK 8
#define ROWS 32

#define HTILE_B (ROWS * HH * 2)               // 32 KiB per cluster per buffer
#define HBUF_B  ((size_t)NCL * HTILE_B)       // 1 MiB per buffer
#define BAR_OFF ((size_t)2 * HBUF_B)
#define WS_USED (BAR_OFF + (size_t)NCL * 128)

#define LDSB (ROWS * 1024)                    // 32 KiB A-tile

#define GAS __attribute__((address_space(1)))
#define LAS __attribute__((address_space(3)))

typedef _Float16 half8 __attribute__((ext_vector_type(8)));
typedef float    f32x4 __attribute__((ext_vector_type(4)));

static __device__ __forceinline__ float fast_sigmoid(float x) {
  float e = exp2f(-1.44269504f * x);
  return __builtin_amdgcn_rcpf(1.0f + e);
}
static __device__ __forceinline__ float fast_tanh(float x) {
  float e = exp2f(2.88539008f * x);           // exp(2x)
  return 1.0f - 2.0f * __builtin_amdgcn_rcpf(1.0f + e);
}

// Poll 8 per-block flag words lane-parallel, relaxed agent (round 8 form).
static __device__ __forceinline__ void wait_flags8(unsigned* f, unsigned tgt,
                                                   int* dead) {
  const int l = threadIdx.x & 63;
  long spin = 0;
  for (;;) {
    unsigned v = __hip_atomic_load(f + (l & 7), __ATOMIC_RELAXED,
                                   __HIP_MEMORY_SCOPE_AGENT);
    if (__all(v >= tgt)) break;
    if (++spin > (1L << 24)) { *dead = 1; break; }
  }
}

__global__ void __launch_bounds__(NT, 1)
gru_persistent(const float* __restrict__ hist,
               const float* __restrict__ w_ih,
               const float* __restrict__ w_hh,
               const float* __restrict__ w_out,
               const float* __restrict__ b_out,
               float* __restrict__ out,
               uint8_t* __restrict__ ws)
{
  extern __shared__ char smem[];
  char* ldsA = smem;
  const int bid = blockIdx.x;
  const int c   = bid & 31;          // cluster (32) — XCD-local (all = c mod 8)
  const int g   = bid >> 5;          // block within cluster (8)
  const int tid = threadIdx.x;
  const int w   = tid >> 6;          // wave 0..3 -> col-tile
  const int l   = tid & 63;
  const int l15 = l & 15;
  const int l4  = l >> 4;
  const int crb = c * ROWS;
  unsigned* flags = (unsigned*)(ws + BAR_OFF) + c * 32;  // 128B line / cluster

  const int col0 = g * 64 + w * 16;  // wave's 16 output cols
  const int pcol = col0 + l15;

  // ---- W_hh register B-fragments for r,z,n (16 K-slices each, static idx)
  half8 wr[16], wz[16], wn[16];
#pragma unroll
  for (int ks = 0; ks < 16; ++ks) {
    const size_t Rr = (size_t)(0 * HH + col0 + l15) * HH + ks * 32 + l4 * 8;
    const size_t Rz = (size_t)(1 * HH + col0 + l15) * HH + ks * 32 + l4 * 8;
    const size_t Rn = (size_t)(2 * HH + col0 + l15) * HH + ks * 32 + l4 * 8;
#pragma unroll
    for (int i = 0; i < 8; ++i) {
      wr[ks][i] = (_Float16)w_hh[Rr + i];
      wz[ks][i] = (_Float16)w_hh[Rz + i];
      wn[ks][i] = (_Float16)w_hh[Rn + i];
    }
  }

  // ---- w_ih register B-fragments (K window = x cols 0..31)
  half8 wih[3];
#pragma unroll
  for (int gt = 0; gt < 3; ++gt) {
    const int R = gt * HH + col0 + l15;
#pragma unroll
    for (int i = 0; i < 8; ++i) {
      const int k = l4 * 8 + i;
      wih[gt][i] = (_Float16)((k < II) ? w_ih[R * II + k] : 0.0f);
    }
  }

  // ---- w_out in registers (round 8 logits layout)
  const int jj = (l >> 4) & 1;
  float wor[32];
#pragma unroll
  for (int i = 0; i < 32; ++i) wor[i] = w_out[jj * HH + l15 * 32 + i];
  const float bo = b_out[jj];

  float hprev[2][4];
#pragma unroll
  for (int mt = 0; mt < 2; ++mt)
#pragma unroll
    for (int q = 0; q < 4; ++q) hprev[mt][q] = 0.0f;

  const int lr = (g * 4 + w) & 31;   // logits row for this wave
  int deadlock = 0;

  // ---- x prologue: prefetch x(0)
  f32x4 xn0[2], xn1[2];
#pragma unroll
  for (int mt = 0; mt < 2; ++mt) {
    xn0[mt] = (f32x4){0.f, 0.f, 0.f, 0.f};
    xn1[mt] = (f32x4){0.f, 0.f, 0.f, 0.f};
    const float* xp = hist + (size_t)(crb + mt * 16 + l15) * (TT * II);
    if (l4 == 0)      { xn0[mt] = *(const f32x4*)xp; xn1[mt] = *(const f32x4*)(xp + 4); }
    else if (l4 == 1) { xn0[mt] = *(const f32x4*)(xp + 8); }
  }

  for (int t = 0; t < TT; ++t) {
    const uint8_t* hsrc = ws + ((t & 1) ? HBUF_B : 0) + (size_t)c * HTILE_B;
    uint8_t*       hdst = ws + ((t & 1) ? 0 : HBUF_B) + (size_t)c * HTILE_B;

    if (t > 0) wait_flags8(flags, (unsigned)t, &deadlock);

    // ---- issue h(t) staging: 8 insts/wave
#pragma unroll
    for (int it = 0; it < 8; ++it)
      __builtin_amdgcn_global_load_lds(
          (const GAS uint32_t*)(hsrc + it * 4096 + tid * 16),
          (LAS uint32_t*)(ldsA + it * 4096 + tid * 16), 16, 0, 17);
    __builtin_amdgcn_sched_barrier(0);

    // ---- build x(t) fragments from last prefetch; issue x(t+1) prefetch
    half8 ax[2];
#pragma unroll
    for (int mt = 0; mt < 2; ++mt)
#pragma unroll
      for (int i = 0; i < 4; ++i) {
        ax[mt][i]     = (_Float16)xn0[mt][i];
        ax[mt][4 + i] = (_Float16)xn1[mt][i];
      }
    {
      const int tx = (t + 1 < TT) ? (t + 1) : 0;
#pragma unroll
      for (int mt = 0; mt < 2; ++mt) {
        const float* xp = hist + (size_t)(crb + mt * 16 + l15) * (TT * II) + (size_t)tx * II;
        if (l4 == 0)      { xn0[mt] = *(const f32x4*)xp; xn1[mt] = *(const f32x4*)(xp + 4); }
        else if (l4 == 1) { xn0[mt] = *(const f32x4*)(xp + 8); }
      }
    }
    __builtin_amdgcn_sched_barrier(0);

    // outstanding/wave: 8 staging + 6 x. vmcnt(10) -> lo (rows 0-15) staged.
    asm volatile("s_waitcnt vmcnt(10)" ::: "memory");
    __builtin_amdgcn_s_barrier();
    __builtin_amdgcn_sched_barrier(0);

    // ======== phase 1: rows 0-15 (mt=0) ========
    f32x4 acc0 = (f32x4){0.f, 0.f, 0.f, 0.f};
    f32x4 acc1 = acc0, acc2 = acc0;
    f32x4 accin = __builtin_amdgcn_mfma_f32_16x16x32_f16(ax[0], wih[2],
                    (f32x4){0.f, 0.f, 0.f, 0.f}, 0, 0, 0);
    acc0 = __builtin_amdgcn_mfma_f32_16x16x32_f16(ax[0], wih[0], acc0, 0, 0, 0);
    acc1 = __builtin_amdgcn_mfma_f32_16x16x32_f16(ax[0], wih[1], acc1, 0, 0, 0);
#pragma unroll
    for (int ks = 0; ks < 16; ++ks) {
      const int ko = (ks * 64 + l4 * 16) ^ (l15 << 4);   // 4-bit swizzle
      half8 a = *(const half8*)(ldsA + l15 * 1024 + ko);
      acc0 = __builtin_amdgcn_mfma_f32_16x16x32_f16(a, wr[ks], acc0, 0, 0, 0);
      acc1 = __builtin_amdgcn_mfma_f32_16x16x32_f16(a, wz[ks], acc1, 0, 0, 0);
      acc2 = __builtin_amdgcn_mfma_f32_16x16x32_f16(a, wn[ks], acc2, 0, 0, 0);
    }
    __builtin_amdgcn_sched_barrier(0);

    // mid: vmcnt(6) -> hi staged (x6 outstanding; no stores yet) -> barrier
    asm volatile("s_waitcnt vmcnt(6)" ::: "memory");
    __builtin_amdgcn_s_barrier();
    __builtin_amdgcn_sched_barrier(0);

    // ======== overlap region: phase-2 MFMAs (separate regs) + gates-lo
    //          VALU + logits — scheduler interleaves across pipes ========
    f32x4 b0 = (f32x4){0.f, 0.f, 0.f, 0.f};
    f32x4 b1 = b0, b2 = b0;
    f32x4 bin = __builtin_amdgcn_mfma_f32_16x16x32_f16(ax[1], wih[2],
                  (f32x4){0.f, 0.f, 0.f, 0.f}, 0, 0, 0);
    b0 = __builtin_amdgcn_mfma_f32_16x16x32_f16(ax[1], wih[0], b0, 0, 0, 0);
    b1 = __builtin_amdgcn_mfma_f32_16x16x32_f16(ax[1], wih[1], b1, 0, 0, 0);
#pragma unroll
    for (int ks = 0; ks < 16; ++ks) {
      const int ko = (ks * 64 + l4 * 16) ^ (l15 << 4);
      half8 a = *(const half8*)(ldsA + (16 + l15) * 1024 + ko);
      b0 = __builtin_amdgcn_mfma_f32_16x16x32_f16(a, wr[ks], b0, 0, 0, 0);
      b1 = __builtin_amdgcn_mfma_f32_16x16x32_f16(a, wz[ks], b1, 0, 0, 0);
      b2 = __builtin_amdgcn_mfma_f32_16x16x32_f16(a, wn[ks], b2, 0, 0, 0);
    }

    // gates + stores rows 0-15 (phase-1 accs; independent of b*)
#pragma unroll
    for (int q = 0; q < 4; ++q) {
      const int m = l4 * 4 + q;
      const float r  = fast_sigmoid(acc0[q]);
      const float z  = fast_sigmoid(acc1[q]);
      const float n  = fast_tanh(accin[q] + r * acc2[q]);
      const float hn = (1.0f - z) * n + z * hprev[0][q];
      hprev[0][q] = hn;
      __hip_atomic_store(
          (unsigned short*)(hdst + m * 1024 + ((pcol * 2) ^ ((m & 15) << 4))),
          __builtin_bit_cast(unsigned short, (_Float16)hn),
          __ATOMIC_RELAXED, __HIP_MEMORY_SCOPE_AGENT);
    }

    // logits(t-1) from ldsA = h(t): row lr, both halves staged & stable
    if (t > 0) {
      float s = 0.0f;
#pragma unroll
      for (int c8 = 0; c8 < 4; ++c8) {
        half8 hv = *(const half8*)(ldsA + lr * 1024 +
                                   ((l15 * 64 + c8 * 16) ^ ((lr & 15) << 4)));
#pragma unroll
        for (int i = 0; i < 8; ++i) s += (float)hv[i] * wor[c8 * 8 + i];
      }
#pragma unroll
      for (int off = 1; off < 16; off <<= 1) s += __shfl_xor(s, off);
      if (l15 == 0 && l < 32) out[((size_t)(crb + lr) * TT + (t - 1)) * 2 + jj] = s + bo;
    }

    // gates + stores rows 16-31 (phase-2 accs)
#pragma unroll
    for (int q = 0; q < 4; ++q) {
      const int m = 16 + l4 * 4 + q;
      const float r  = fast_sigmoid(b0[q]);
      const float z  = fast_sigmoid(b1[q]);
      const float n  = fast_tanh(bin[q] + r * b2[q]);
      const float hn = (1.0f - z) * n + z * hprev[1][q];
      hprev[1][q] = hn;
      __hip_atomic_store(
          (unsigned short*)(hdst + m * 1024 + ((pcol * 2) ^ ((m & 15) << 4))),
          __builtin_bit_cast(unsigned short, (_Float16)hn),
          __ATOMIC_RELAXED, __HIP_MEMORY_SCOPE_AGENT);
    }
    __builtin_amdgcn_sched_barrier(0);

    // ---- drain stores (+x), post per-block flag (round 8 form)
    asm volatile("s_waitcnt vmcnt(0)" ::: "memory");
    __builtin_amdgcn_s_barrier();
    if (tid == 0)
      __hip_atomic_store(flags + g, (unsigned)(t + 1), __ATOMIC_RELAXED,
                         __HIP_MEMORY_SCOPE_AGENT);
  }

  // ---- epilogue: stage h(TT), logits for t = TT-1, h_final
  wait_flags8(flags, (unsigned)TT, &deadlock);
  {
    const uint8_t* hsrc = ws + ((TT & 1) ? HBUF_B : 0) + (size_t)c * HTILE_B;
#pragma unroll
    for (int it = 0; it < 8; ++it)
      __builtin_amdgcn_global_load_lds(
          (const GAS uint32_t*)(hsrc + it * 4096 + tid * 16),
          (LAS uint32_t*)(ldsA + it * 4096 + tid * 16), 16, 0, 17);
    asm volatile("s_waitcnt vmcnt(0)" ::: "memory");
    __builtin_amdgcn_s_barrier();

    float s = 0.0f;
#pragma unroll
    for (int c8 = 0; c8 < 4; ++c8) {
      half8 hv = *(const half8*)(ldsA + lr * 1024 +
                                 ((l15 * 64 + c8 * 16) ^ ((lr & 15) << 4)));
#pragma unroll
      for (int i = 0; i < 8; ++i) s += (float)hv[i] * wor[c8 * 8 + i];
    }
#pragma unroll
    for (int off = 1; off < 16; off <<= 1) s += __shfl_xor(s, off);
    if (l15 == 0 && l < 32) out[((size_t)(crb + lr) * TT + (TT - 1)) * 2 + jj] = s + bo;
  }

  // ---- h_final from fp32 carried state
#pragma unroll
  for (int mt = 0; mt < 2; ++mt)
#pragma unroll
    for (int q = 0; q < 4; ++q) {
      const int m = mt * 16 + l4 * 4 + q;
      out[(size_t)TB * TT * 2 + (size_t)(crb + m) * HH + pcol] = hprev[mt][q];
    }
}

extern "C" void kernel_launch(void* const* d_in, const int* in_sizes, int n_in,
                              void* d_out, int out_size, void* d_ws, size_t ws_size,
                              hipStream_t stream) {
  (void)in_sizes; (void)n_in; (void)out_size;
  if (ws_size < WS_USED) return;

  const float* hist  = (const float*)d_in[0];
  const float* w_ih  = (const float*)d_in[1];
  const float* w_hh  = (const float*)d_in[2];
  const float* w_out = (const float*)d_in[3];
  const float* b_out = (const float*)d_in[4];
  float* out = (float*)d_out;
  uint8_t* ws = (uint8_t*)d_ws;

  hipMemsetAsync(d_ws, 0, WS_USED, stream);   // h0 = 0, flag words

  void* args[] = {(void*)&hist, (void*)&w_ih, (void*)&w_hh, (void*)&w_out,
                  (void*)&b_out, (void*)&out, (void*)&ws};
  hipError_t e = hipLaunchCooperativeKernel((const void*)gru_persistent,
                                            dim3(NB), dim3(NT), args,
                                            (unsigned)LDSB, stream);
  if (e != hipSuccess) {
    // Fallback: plain launch. 256 blocks at 1/CU co-reside; every spin loop
    // has a deadlock bail-out so this cannot hang.
    gru_persistent<<<dim3(NB), dim3(NT), LDSB, stream>>>(
        hist, w_ih, w_hh, w_out, b_out, out, ws);
  }
}

// Round 17
// 7649.195 us; speedup vs baseline: 1.6800x; 1.0379x over previous
//
#include <hip/hip_runtime.h>
#include <stdint.h>

// GRU scan, persistent cooperative kernel, round 17.
// = round 8 VERBATIM (best measured: 7.63ms; NB=256, 1 block/CU, 32 clusters
// x 32 rows x 8 blocks, c=bid&31 -> XCD-local, 2-phase with gates issued
// immediately per phase, fresh 8-word poll, per-block flag posted by tid0
// after end barrier, logits at step end) + ONE change, counter-verified in
// r15/r16: 4-bit LDS swizzle (row&15)<<4 (was (row&7)<<4) — cuts
// SQ_LDS_BANK_CONFLICT 3.7e8 -> 1.0e8 (8-way -> 4-way on ds_read_b128).
// All r9-r16 structural variants (skew, ledger re-orders, TLP, XCD remap,
// per-wave flags, VALU-overlap region) measured neutral-to-negative and are
// NOT carried.
// Coherence (proven r5-r16): write-through h stores (RELAXED/AGENT), aux=17
// read-through staging, relaxed flags, no fences.

#define NB 256
#define NT 256
#define TB 1024
#define TT 2048
#define II 12
#define HH 512
#define NCL 32
#define GBLK 8
#define ROWS 32

#define HTILE_B (ROWS * HH * 2)               // 32 KiB per cluster per buffer
#define HBUF_B  ((size_t)NCL * HTILE_B)       // 1 MiB per buffer
#define BAR_OFF ((size_t)2 * HBUF_B)
#define WS_USED (BAR_OFF + (size_t)NCL * 128)

#define LDSB (ROWS * 1024)                    // 32 KiB A-tile

#define GAS __attribute__((address_space(1)))
#define LAS __attribute__((address_space(3)))

typedef _Float16 half8 __attribute__((ext_vector_type(8)));
typedef float    f32x4 __attribute__((ext_vector_type(4)));

static __device__ __forceinline__ float fast_sigmoid(float x) {
  float e = exp2f(-1.44269504f * x);
  return __builtin_amdgcn_rcpf(1.0f + e);
}
static __device__ __forceinline__ float fast_tanh(float x) {
  float e = exp2f(2.88539008f * x);           // exp(2x)
  return 1.0f - 2.0f * __builtin_amdgcn_rcpf(1.0f + e);
}

// Poll 8 per-block flag words (one 32B span) lane-parallel, relaxed.
static __device__ __forceinline__ void wait_flags8(unsigned* f, unsigned tgt,
                                                   int* dead) {
  const int l = threadIdx.x & 63;
  long spin = 0;
  for (;;) {
    unsigned v = __hip_atomic_load(f + (l & 7), __ATOMIC_RELAXED,
                                   __HIP_MEMORY_SCOPE_AGENT);
    if (__all(v >= tgt)) break;
    if (++spin > (1L << 24)) { *dead = 1; break; }
  }
}

__global__ void __launch_bounds__(NT, 1)
gru_persistent(const float* __restrict__ hist,
               const float* __restrict__ w_ih,
               const float* __restrict__ w_hh,
               const float* __restrict__ w_out,
               const float* __restrict__ b_out,
               float* __restrict__ out,
               uint8_t* __restrict__ ws)
{
  extern __shared__ char smem[];
  char* ldsA = smem;
  const int bid = blockIdx.x;
  const int c   = bid & 31;          // cluster (32) — XCD-local (all = c mod 8)
  const int g   = bid >> 5;          // block within cluster (8)
  const int tid = threadIdx.x;
  const int w   = tid >> 6;          // wave 0..3 -> col-tile
  const int l   = tid & 63;
  const int l15 = l & 15;
  const int l4  = l >> 4;
  const int crb = c * ROWS;
  unsigned* flags = (unsigned*)(ws + BAR_OFF) + c * 32;  // 128B line / cluster

  const int col0 = g * 64 + w * 16;  // wave's 16 output cols
  const int pcol = col0 + l15;

  // ---- W_hh register B-fragments for r,z,n (16 K-slices each, static idx)
  half8 wr[16], wz[16], wn[16];
#pragma unroll
  for (int ks = 0; ks < 16; ++ks) {
    const size_t Rr = (size_t)(0 * HH + col0 + l15) * HH + ks * 32 + l4 * 8;
    const size_t Rz = (size_t)(1 * HH + col0 + l15) * HH + ks * 32 + l4 * 8;
    const size_t Rn = (size_t)(2 * HH + col0 + l15) * HH + ks * 32 + l4 * 8;
#pragma unroll
    for (int i = 0; i < 8; ++i) {
      wr[ks][i] = (_Float16)w_hh[Rr + i];
      wz[ks][i] = (_Float16)w_hh[Rz + i];
      wn[ks][i] = (_Float16)w_hh[Rn + i];
    }
  }

  // ---- w_ih register B-fragments (K window = x cols 0..31)
  half8 wih[3];
#pragma unroll
  for (int gt = 0; gt < 3; ++gt) {
    const int R = gt * HH + col0 + l15;
#pragma unroll
    for (int i = 0; i < 8; ++i) {
      const int k = l4 * 8 + i;
      wih[gt][i] = (_Float16)((k < II) ? w_ih[R * II + k] : 0.0f);
    }
  }

  // ---- w_out in registers
  const int jj = (l >> 4) & 1;
  float wor[32];
#pragma unroll
  for (int i = 0; i < 32; ++i) wor[i] = w_out[jj * HH + l15 * 32 + i];
  const float bo = b_out[jj];

  float hprev[2][4];
#pragma unroll
  for (int mt = 0; mt < 2; ++mt)
#pragma unroll
    for (int q = 0; q < 4; ++q) hprev[mt][q] = 0.0f;

  const int lr = (g * 4 + w) & 31;   // logits row for this wave
  int deadlock = 0;

  // ---- x prologue: prefetch x(0)
  f32x4 xn0[2], xn1[2];
#pragma unroll
  for (int mt = 0; mt < 2; ++mt) {
    xn0[mt] = (f32x4){0.f, 0.f, 0.f, 0.f};
    xn1[mt] = (f32x4){0.f, 0.f, 0.f, 0.f};
    const float* xp = hist + (size_t)(crb + mt * 16 + l15) * (TT * II);
    if (l4 == 0)      { xn0[mt] = *(const f32x4*)xp; xn1[mt] = *(const f32x4*)(xp + 4); }
    else if (l4 == 1) { xn0[mt] = *(const f32x4*)(xp + 8); }
  }

  for (int t = 0; t < TT; ++t) {
    const uint8_t* hsrc = ws + ((t & 1) ? HBUF_B : 0) + (size_t)c * HTILE_B;
    uint8_t*       hdst = ws + ((t & 1) ? 0 : HBUF_B) + (size_t)c * HTILE_B;

    if (t > 0) wait_flags8(flags, (unsigned)t, &deadlock);

    // ---- issue h(t) staging: 8 insts/wave
#pragma unroll
    for (int it = 0; it < 8; ++it)
      __builtin_amdgcn_global_load_lds(
          (const GAS uint32_t*)(hsrc + it * 4096 + tid * 16),
          (LAS uint32_t*)(ldsA + it * 4096 + tid * 16), 16, 0, 17);
    __builtin_amdgcn_sched_barrier(0);

    // ---- build x(t) fragments from last prefetch; issue x(t+1) prefetch
    half8 ax[2];
#pragma unroll
    for (int mt = 0; mt < 2; ++mt)
#pragma unroll
      for (int i = 0; i < 4; ++i) {
        ax[mt][i]     = (_Float16)xn0[mt][i];
        ax[mt][4 + i] = (_Float16)xn1[mt][i];
      }
    {
      const int tx = (t + 1 < TT) ? (t + 1) : 0;
#pragma unroll
      for (int mt = 0; mt < 2; ++mt) {
        const float* xp = hist + (size_t)(crb + mt * 16 + l15) * (TT * II) + (size_t)tx * II;
        if (l4 == 0)      { xn0[mt] = *(const f32x4*)xp; xn1[mt] = *(const f32x4*)(xp + 4); }
        else if (l4 == 1) { xn0[mt] = *(const f32x4*)(xp + 8); }
      }
    }
    __builtin_amdgcn_sched_barrier(0);

    // outstanding/wave: 8 staging + 6 x. vmcnt(10) -> lo (rows 0-15) staged.
    asm volatile("s_waitcnt vmcnt(10)" ::: "memory");
    __builtin_amdgcn_s_barrier();
    __builtin_amdgcn_sched_barrier(0);

    f32x4 acc0, acc1, acc2, accin;

    // ======== phase 1: rows 0-15 (mt=0) ========
    acc0 = (f32x4){0.f, 0.f, 0.f, 0.f};
    acc1 = acc0; acc2 = acc0;
    accin = __builtin_amdgcn_mfma_f32_16x16x32_f16(ax[0], wih[2],
              (f32x4){0.f, 0.f, 0.f, 0.f}, 0, 0, 0);
    acc0 = __builtin_amdgcn_mfma_f32_16x16x32_f16(ax[0], wih[0], acc0, 0, 0, 0);
    acc1 = __builtin_amdgcn_mfma_f32_16x16x32_f16(ax[0], wih[1], acc1, 0, 0, 0);
#pragma unroll
    for (int ks = 0; ks < 16; ++ks) {
      const int ko = (ks * 64 + l4 * 16) ^ (l15 << 4);   // 4-bit swizzle
      half8 a = *(const half8*)(ldsA + l15 * 1024 + ko);
      acc0 = __builtin_amdgcn_mfma_f32_16x16x32_f16(a, wr[ks], acc0, 0, 0, 0);
      acc1 = __builtin_amdgcn_mfma_f32_16x16x32_f16(a, wz[ks], acc1, 0, 0, 0);
      acc2 = __builtin_amdgcn_mfma_f32_16x16x32_f16(a, wn[ks], acc2, 0, 0, 0);
    }
#pragma unroll
    for (int q = 0; q < 4; ++q) {
      const int m = l4 * 4 + q;                       // rows 0-15
      const float r  = fast_sigmoid(acc0[q]);
      const float z  = fast_sigmoid(acc1[q]);
      const float n  = fast_tanh(accin[q] + r * acc2[q]);
      const float hn = (1.0f - z) * n + z * hprev[0][q];
      hprev[0][q] = hn;
      __hip_atomic_store(
          (unsigned short*)(hdst + m * 1024 + ((pcol * 2) ^ ((m & 15) << 4))),
          __builtin_bit_cast(unsigned short, (_Float16)hn),
          __ATOMIC_RELAXED, __HIP_MEMORY_SCOPE_AGENT);
    }
    __builtin_amdgcn_sched_barrier(0);

    // outstanding: 4 hi staging + 6 x + 4 stores. vmcnt(10) -> hi staged.
    asm volatile("s_waitcnt vmcnt(10)" ::: "memory");
    __builtin_amdgcn_s_barrier();
    __builtin_amdgcn_sched_barrier(0);

    // ======== phase 2: rows 16-31 (mt=1) ========
    acc0 = (f32x4){0.f, 0.f, 0.f, 0.f};
    acc1 = acc0; acc2 = acc0;
    accin = __builtin_amdgcn_mfma_f32_16x16x32_f16(ax[1], wih[2],
              (f32x4){0.f, 0.f, 0.f, 0.f}, 0, 0, 0);
    acc0 = __builtin_amdgcn_mfma_f32_16x16x32_f16(ax[1], wih[0], acc0, 0, 0, 0);
    acc1 = __builtin_amdgcn_mfma_f32_16x16x32_f16(ax[1], wih[1], acc1, 0, 0, 0);
#pragma unroll
    for (int ks = 0; ks < 16; ++ks) {
      const int ko = (ks * 64 + l4 * 16) ^ (l15 << 4);   // (row&15)=l15 here too
      half8 a = *(const half8*)(ldsA + (16 + l15) * 1024 + ko);
      acc0 = __builtin_amdgcn_mfma_f32_16x16x32_f16(a, wr[ks], acc0, 0, 0, 0);
      acc1 = __builtin_amdgcn_mfma_f32_16x16x32_f16(a, wz[ks], acc1, 0, 0, 0);
      acc2 = __builtin_amdgcn_mfma_f32_16x16x32_f16(a, wn[ks], acc2, 0, 0, 0);
    }
#pragma unroll
    for (int q = 0; q < 4; ++q) {
      const int m = 16 + l4 * 4 + q;                  // rows 16-31
      const float r  = fast_sigmoid(acc0[q]);
      const float z  = fast_sigmoid(acc1[q]);
      const float n  = fast_tanh(accin[q] + r * acc2[q]);
      const float hn = (1.0f - z) * n + z * hprev[1][q];
      hprev[1][q] = hn;
      __hip_atomic_store(
          (unsigned short*)(hdst + m * 1024 + ((pcol * 2) ^ ((m & 15) << 4))),
          __builtin_bit_cast(unsigned short, (_Float16)hn),
          __ATOMIC_RELAXED, __HIP_MEMORY_SCOPE_AGENT);
    }

    // ---- logits for step t-1 from ldsA = h(t); row lr, wave-private
    if (t > 0) {
      float s = 0.0f;
#pragma unroll
      for (int c8 = 0; c8 < 4; ++c8) {
        half8 hv = *(const half8*)(ldsA + lr * 1024 +
                                   ((l15 * 64 + c8 * 16) ^ ((lr & 15) << 4)));
#pragma unroll
        for (int i = 0; i < 8; ++i) s += (float)hv[i] * wor[c8 * 8 + i];
      }
#pragma unroll
      for (int off = 1; off < 16; off <<= 1) s += __shfl_xor(s, off);
      if (l15 == 0 && l < 32) out[((size_t)(crb + lr) * TT + (t - 1)) * 2 + jj] = s + bo;
    }

    // ---- drain stores (+x), post per-block flag (plain write-through)
    asm volatile("s_waitcnt vmcnt(0)" ::: "memory");
    __builtin_amdgcn_s_barrier();
    if (tid == 0)
      __hip_atomic_store(flags + g, (unsigned)(t + 1), __ATOMIC_RELAXED,
                         __HIP_MEMORY_SCOPE_AGENT);
  }

  // ---- epilogue: stage h(TT), logits for t = TT-1, h_final
  wait_flags8(flags, (unsigned)TT, &deadlock);
  {
    const uint8_t* hsrc = ws + ((TT & 1) ? HBUF_B : 0) + (size_t)c * HTILE_B;
#pragma unroll
    for (int it = 0; it < 8; ++it)
      __builtin_amdgcn_global_load_lds(
          (const GAS uint32_t*)(hsrc + it * 4096 + tid * 16),
          (LAS uint32_t*)(ldsA + it * 4096 + tid * 16), 16, 0, 17);
    asm volatile("s_waitcnt vmcnt(0)" ::: "memory");
    __builtin_amdgcn_s_barrier();

    float s = 0.0f;
#pragma unroll
    for (int c8 = 0; c8 < 4; ++c8) {
      half8 hv = *(const half8*)(ldsA + lr * 1024 +
                                 ((l15 * 64 + c8 * 16) ^ ((lr & 15) << 4)));
#pragma unroll
      for (int i = 0; i < 8; ++i) s += (float)hv[i] * wor[c8 * 8 + i];
    }
#pragma unroll
    for (int off = 1; off < 16; off <<= 1) s += __shfl_xor(s, off);
    if (l15 == 0 && l < 32) out[((size_t)(crb + lr) * TT + (TT - 1)) * 2 + jj] = s + bo;
  }

  // ---- h_final from fp32 carried state
#pragma unroll
  for (int mt = 0; mt < 2; ++mt)
#pragma unroll
    for (int q = 0; q < 4; ++q) {
      const int m = mt * 16 + l4 * 4 + q;
      out[(size_t)TB * TT * 2 + (size_t)(crb + m) * HH + pcol] = hprev[mt][q];
    }
}

extern "C" void kernel_launch(void* const* d_in, const int* in_sizes, int n_in,
                              void* d_out, int out_size, void* d_ws, size_t ws_size,
                              hipStream_t stream) {
  (void)in_sizes; (void)n_in; (void)out_size;
  if (ws_size < WS_USED) return;

  const float* hist  = (const float*)d_in[0];
  const float* w_ih  = (const float*)d_in[1];
  const float* w_hh  = (const float*)d_in[2];
  const float* w_out = (const float*)d_in[3];
  const float* b_out = (const float*)d_in[4];
  float* out = (float*)d_out;
  uint8_t* ws = (uint8_t*)d_ws;

  hipMemsetAsync(d_ws, 0, WS_USED, stream);   // h0 = 0, flag words

  void* args[] = {(void*)&hist, (void*)&w_ih, (void*)&w_hh, (void*)&w_out,
                  (void*)&b_out, (void*)&out, (void*)&ws};
  hipError_t e = hipLaunchCooperativeKernel((const void*)gru_persistent,
                                            dim3(NB), dim3(NT), args,
                                            (unsigned)LDSB, stream);
  if (e != hipSuccess) {
    // Fallback: plain launch. 256 blocks at 1/CU co-reside; every spin loop
    // has a deadlock bail-out so this cannot hang.
    gru_persistent<<<dim3(NB), dim3(NT), LDSB, stream>>>(
        hist, w_ih, w_hh, w_out, b_out, out, ws);
  }
}